// Round 8
// baseline (112.440 us; speedup 1.0000x reference)
//
#include <hip/hip_runtime.h>

#define BATCH  4
#define NPTS   4096
#define NSKEL  100
#define KNN    10
#define SPLIT  64                 // lanes per query-group = full wave
#define CPT    (NPTS / SPLIT)     // 64 candidates per thread
#define CPAD   (CPT + 1)          // padded chunk stride (65 = 1 mod 8 -> conflict-free)
#define QPB    32                 // 16 waves/block * 2 queries/wave
#define BIG    3.0e38f

__device__ __forceinline__ float med3f(float a, float b, float c) {
#if __has_builtin(__builtin_amdgcn_fmed3f)
    return __builtin_amdgcn_fmed3f(a, b, c);
#else
    float d;
    asm("v_med3_f32 %0, %1, %2, %3" : "=v"(d) : "v"(a), "v"(b), "v"(c));
    return d;
#endif
}

#define CE(a,i,j) do { float _lo = fminf(a[i],a[j]); a[j] = fmaxf(a[i],a[j]); a[i] = _lo; } while (0)

// Merge my ascending 10-list with lane^mask's via bitonic half-cleaner (keep
// the 10 smallest of 20), then re-sort with the 15-CE network (validated
// R3-R7: absmax 0). After a round, lanes i and i^mask hold identical lists.
__device__ __forceinline__ void merge_round(float l[KNN], int mask) {
    float c[KNN];
#pragma unroll
    for (int i = 0; i < KNN; ++i) {
        float o = __shfl_xor(l[KNN - 1 - i], mask, 64);
        c[i] = fminf(l[i], o);
    }
    CE(c,0,8); CE(c,1,9);
    CE(c,2,6); CE(c,3,7); CE(c,4,8); CE(c,5,9);
    CE(c,2,4); CE(c,3,5); CE(c,6,8); CE(c,7,9); CE(c,0,1);
    CE(c,2,3); CE(c,4,5); CE(c,6,7); CE(c,8,9);
#pragma unroll
    for (int i = 0; i < KNN; ++i) l[i] = c[i];
}

// padded LDS index for global point id j (chunk = j>>6 gets +1 float4 each)
#define PIDX(j) ((j) + ((j) >> 6))

__global__ __launch_bounds__(1024, 8) void voronoi_kernel(const float* __restrict__ xyz,
                                                          const float* __restrict__ skel,
                                                          float* __restrict__ out) {
    __shared__ float4 spts[NPTS + SPLIT];  // padded chunks, 65 KB
    __shared__ float4 sskl[NSKEL];
    __shared__ float  part[16];

    const int tid = threadIdx.x;
    const int b   = blockIdx.x >> 7;            // 128 blocks per batch
    const int qb  = (blockIdx.x & 127) * QPB;   // 32 queries per block
    const float* xb = xyz  + (size_t)b * NPTS * 6;
    const float* sb = skel + (size_t)b * NSKEL * 3;

    // Stage 2 points per iter via 3 coalesced float4 loads (2 iterations)
    for (int p2 = tid; p2 < NPTS / 2; p2 += 1024) {
        const float4* row = (const float4*)(xb + p2 * 12);
        float4 A = row[0], Bv = row[1], Cv = row[2];
        int i0 = 2 * p2;
        spts[PIDX(i0)]     = make_float4(A.x, A.y, A.z,
                                         fmaf(A.z, A.z, fmaf(A.y, A.y, A.x * A.x)));
        spts[PIDX(i0 + 1)] = make_float4(Bv.z, Bv.w, Cv.x,
                                         fmaf(Cv.x, Cv.x, fmaf(Bv.w, Bv.w, Bv.z * Bv.z)));
    }
    if (tid < NSKEL) {
        float x = sb[tid*3+0], y = sb[tid*3+1], z = sb[tid*3+2];
        sskl[tid] = make_float4(x, y, z, x*x + y*y + z*z);
    }
    __syncthreads();

    const int split = tid & 63;                // lane within the wave-group
    const int group = tid >> 6;                // wave id 0..15
    const int q0i   = qb + group * 2;
    const float4 Q0 = spts[PIDX(q0i)];
    const float4 Q1 = spts[PIDX(q0i + 1)];
    // score = |c|^2 - 2 q.c  (monotone map of d2; d2 gap == score gap)
    const float n0x = -2.f*Q0.x, n0y = -2.f*Q0.y, n0z = -2.f*Q0.z;
    const float n1x = -2.f*Q1.x, n1y = -2.f*Q1.y, n1z = -2.f*Q1.z;

    float l0[KNN], l1[KNN];
#pragma unroll
    for (int k = 0; k < KNN; ++k) { l0[k] = BIG; l1[k] = BIG; }

    const int jb = split * CPT;
    const float4* chunk = spts + split * CPAD;  // base = split mod 8 phase-distinct

    float4 A4[4], B4[4];
#pragma unroll
    for (int u = 0; u < 4; ++u) A4[u] = chunk[u];

    auto PROC = [&](const float4* buf, int t) {
#pragma unroll
        for (int u = 0; u < 4; ++u) {
            float4 cc = buf[u];
            float s0 = fmaf(n0z, cc.z, fmaf(n0y, cc.y, fmaf(n0x, cc.x, cc.w)));
            float s1 = fmaf(n1z, cc.z, fmaf(n1y, cc.y, fmaf(n1x, cc.x, cc.w)));
            unsigned j = (unsigned)(jb + t + u);
            float f0 = __uint_as_float((__float_as_uint(s0) & ~0xFFFu) | (j & 0xFFFu));
            float f1 = __uint_as_float((__float_as_uint(s1) & ~0xFFFu) | (j & 0xFFFu));
#pragma unroll
            for (int k = KNN - 1; k >= 1; --k) l0[k] = med3f(f0, l0[k-1], l0[k]);
            l0[0] = fminf(f0, l0[0]);
#pragma unroll
            for (int k = KNN - 1; k >= 1; --k) l1[k] = med3f(f1, l1[k-1], l1[k]);
            l1[0] = fminf(f1, l1[0]);
        }
    };

    // Double-buffered scan: next 4 candidates' ds_read_b128 issue before
    // processing the current 4.  CPT=64 -> 8 iterations.
#pragma unroll 1
    for (int t = 0; t < CPT; t += 8) {
#pragma unroll
        for (int u = 0; u < 4; ++u) B4[u] = chunk[t + 4 + u];
        PROC(A4, t);
        if (t + 8 < CPT) {
#pragma unroll
            for (int u = 0; u < 4; ++u) A4[u] = chunk[t + 8 + u];
        }
        PROC(B4, t + 4);
    }

    // ---- merge: 1 paired round, select parity, then 5 single-list rounds ----
    merge_round(l0, 1);
    merge_round(l1, 1);
    const int sel = split & 1;
    float ml[KNN];
#pragma unroll
    for (int k = 0; k < KNN; ++k) ml[k] = sel ? l1[k] : l0[k];
    merge_round(ml, 2); merge_round(ml, 4); merge_round(ml, 8);
    merge_round(ml, 16); merge_round(ml, 32);
    // every even lane holds q0's sorted top-10, every odd lane q1's

    // ---- distributed changingrate: lane (sel, kk) handles neighbor kk ----
    const int kk  = split >> 1;       // 0..31
    const int myq = q0i + sel;
    float crk = 0.0f;
    if (kk < KNN) {
        float mlk = BIG;
#pragma unroll
        for (int k = 0; k < KNN; ++k) mlk = (kk == k) ? ml[k] : mlk;  // static select
        int j = (int)(__float_as_uint(mlk) & 0xFFFu);
        float nx = xb[myq*6+3], ny = xb[myq*6+4], nz = xb[myq*6+5];
        float mx = xb[j*6+3],  my_ = xb[j*6+4],  mz = xb[j*6+5];
        float cx = ny*mz - nz*my_;
        float cy = nz*mx - nx*mz;
        float cz = nx*my_ - ny*mx;
        float c1 = sqrtf(cx*cx + cy*cy + cz*cz);
        float px = nx*mx, py = ny*my_, pz = nz*mz;
        float c2 = sqrtf(px*px + py*py + pz*pz);
        crk = fminf(c1, c2);
    }
#pragma unroll
    for (int m = 2; m <= 32; m <<= 1) crk += __shfl_xor(crk, m, 64);

    // ---- top-2 skeleton scores for my parity query (32-lane split) ----
    const float nqx = sel ? n1x : n0x;
    const float nqy = sel ? n1y : n0y;
    const float nqz = sel ? n1z : n0z;
    float t0v = BIG, t1v = BIG;
    for (int m = kk; m < NSKEL; m += 32) {
        float4 c = sskl[m];
        float s = fmaf(nqz, c.z, fmaf(nqy, c.y, fmaf(nqx, c.x, c.w)));
        t1v = med3f(s, t0v, t1v);    // uses old t0v
        t0v = fminf(s, t0v);
    }
#pragma unroll
    for (int m = 2; m <= 32; m <<= 1) {
        float o0 = __shfl_xor(t0v, m, 64);
        float o1 = __shfl_xor(t1v, m, 64);
        float nv = fminf(fmaxf(t0v, o0), fminf(t1v, o1));
        t0v = fminf(t0v, o0); t1v = nv;
    }
    // owners: split 0 -> q0, split 1 -> q1
    float contrib = (split < 2) ? crk * (t1v - t0v) : 0.0f;

#pragma unroll
    for (int o = 32; o > 0; o >>= 1) contrib += __shfl_down(contrib, o);
    if ((tid & 63) == 0) part[tid >> 6] = contrib;
    __syncthreads();
    if (tid == 0) {
        float s = 0.0f;
#pragma unroll
        for (int i = 0; i < 16; ++i) s += part[i];
        atomicAdd(out, s);
    }

    // ---- skeleton self-NN term, one block per batch ----
    if ((blockIdx.x & 127) == 0) {
        float v = 0.0f;
        if (tid < NSKEL) {
            float4 sq = sskl[tid];
            float b0 = BIG, b1 = BIG; int i0 = 0, i1 = 0;
            for (int jj = 0; jj < NSKEL; ++jj) {
                float4 c = sskl[jj];
                float s = c.w - 2.0f*(sq.x*c.x + sq.y*c.y + sq.z*c.z);
                if (s < b0)      { b1 = b0; i1 = i0; b0 = s; i0 = jj; }
                else if (s < b1) { b1 = s; i1 = jj; }
            }
            float4 c = sskl[i1];                 // knn_skele[..., 1]
            float dx = sq.x - c.x, dy = sq.y - c.y, dz = sq.z - c.z;
            v = sqrtf(dx*dx + dy*dy + dz*dz);
        }
#pragma unroll
        for (int o = 32; o > 0; o >>= 1) v += __shfl_down(v, o);
        if ((tid & 63) == 0 && tid < 128) atomicAdd(out, -0.5f * v);
    }
}

extern "C" void kernel_launch(void* const* d_in, const int* in_sizes, int n_in,
                              void* d_out, int out_size, void* d_ws, size_t ws_size,
                              hipStream_t stream) {
    const float* xyz  = (const float*)d_in[0];
    // d_in[1] = num_class (== NSKEL), compile-time constant here
    const float* skel = (const float*)d_in[2];
    float* out = (float*)d_out;

    hipMemsetAsync(out, 0, sizeof(float), stream);
    voronoi_kernel<<<BATCH * 128, 1024, 0, stream>>>(xyz, skel, out);
}

// Round 9
// 61.645 us; speedup vs baseline: 1.8240x; 1.8240x over previous
//
#include <hip/hip_runtime.h>

#define BATCH  4
#define NPTS   4096
#define NSKEL  100
#define KNN    10
#define SPLIT  32                 // lanes per query-group
#define NCH    64                 // candidate chunks (2 halves x 32 lanes)
#define CPT    (NPTS / NCH)       // 64 candidates per thread
#define CPAD   (CPT + 1)          // padded chunk stride (65 = 1 mod 8)
#define QPB    32                 // queries per block (16 pairs x 2)
#define BIG    3.0e38f

__device__ __forceinline__ float med3f(float a, float b, float c) {
#if __has_builtin(__builtin_amdgcn_fmed3f)
    return __builtin_amdgcn_fmed3f(a, b, c);
#else
    float d;
    asm("v_med3_f32 %0, %1, %2, %3" : "=v"(d) : "v"(a), "v"(b), "v"(c));
    return d;
#endif
}

#define CE(a,i,j) do { float _lo = fminf(a[i],a[j]); a[j] = fmaxf(a[i],a[j]); a[i] = _lo; } while (0)
#define SORT10(c) do { \
    CE(c,0,8); CE(c,1,9); \
    CE(c,2,6); CE(c,3,7); CE(c,4,8); CE(c,5,9); \
    CE(c,2,4); CE(c,3,5); CE(c,6,8); CE(c,7,9); CE(c,0,1); \
    CE(c,2,3); CE(c,4,5); CE(c,6,7); CE(c,8,9); } while (0)

// Merge my ascending 10-list with lane^mask's via bitonic half-cleaner (keep
// the 10 smallest of 20), then re-sort with the 15-CE network (validated
// R3-R8: absmax 0). After a round, lanes i and i^mask hold identical lists.
__device__ __forceinline__ void merge_round(float l[KNN], int mask) {
    float c[KNN];
#pragma unroll
    for (int i = 0; i < KNN; ++i) {
        float o = __shfl_xor(l[KNN - 1 - i], mask, 64);
        c[i] = fminf(l[i], o);
    }
    SORT10(c);
#pragma unroll
    for (int i = 0; i < KNN; ++i) l[i] = c[i];
}

// padded LDS index for global point id j (chunk = j>>6 gets +1 float4 each)
#define PIDX(j) ((j) + ((j) >> 6))

__global__ __launch_bounds__(1024, 4) void voronoi_kernel(const float* __restrict__ xyz,
                                                          const float* __restrict__ skel,
                                                          float* __restrict__ out) {
    __shared__ float4 spts[NPTS + NCH];   // padded chunks, 65 KB
    __shared__ float4 sskl[NSKEL];
    __shared__ float  plist[16][2][KNN];  // half-1 partial lists
    __shared__ float  qlists[QPB][KNN];   // final merged lists
    __shared__ float  part[16];

    const int tid = threadIdx.x;
    const int b   = blockIdx.x >> 7;            // 128 blocks per batch
    const int qb  = (blockIdx.x & 127) * QPB;   // 32 queries per block
    const float* xb = xyz  + (size_t)b * NPTS * 6;
    const float* sb = skel + (size_t)b * NSKEL * 3;

    // Stage 2 points per iter via 3 coalesced float4 loads (2 iterations)
    for (int p2 = tid; p2 < NPTS / 2; p2 += 1024) {
        const float4* row = (const float4*)(xb + p2 * 12);
        float4 A = row[0], Bv = row[1], Cv = row[2];
        int i0 = 2 * p2;
        spts[PIDX(i0)]     = make_float4(A.x, A.y, A.z,
                                         fmaf(A.z, A.z, fmaf(A.y, A.y, A.x * A.x)));
        spts[PIDX(i0 + 1)] = make_float4(Bv.z, Bv.w, Cv.x,
                                         fmaf(Cv.x, Cv.x, fmaf(Bv.w, Bv.w, Bv.z * Bv.z)));
    }
    if (tid < NSKEL) {
        float x = sb[tid*3+0], y = sb[tid*3+1], z = sb[tid*3+2];
        sskl[tid] = make_float4(x, y, z, x*x + y*y + z*z);
    }
    __syncthreads();

    const int split = tid & 31;
    const int group = tid >> 5;            // 0..31
    const int half  = group >> 4;          // 0 or 1: candidate half
    const int qpair = group & 15;          // query-pair id
    const int q0i   = qb + qpair * 2;
    const float4 Q0 = spts[PIDX(q0i)];
    const float4 Q1 = spts[PIDX(q0i + 1)];
    // score = |c|^2 - 2 q.c  (monotone map of d2; d2 gap == score gap)
    const float n0x = -2.f*Q0.x, n0y = -2.f*Q0.y, n0z = -2.f*Q0.z;
    const float n1x = -2.f*Q1.x, n1y = -2.f*Q1.y, n1z = -2.f*Q1.z;

    float l0[KNN], l1[KNN];
#pragma unroll
    for (int k = 0; k < KNN; ++k) { l0[k] = BIG; l1[k] = BIG; }

    const int ch = split + (half << 5);    // chunk 0..63
    const int jb = ch * CPT;
    const float4* chunk = spts + ch * CPAD;  // base bank-quad = ch%8

    float4 A4[4], B4[4];
#pragma unroll
    for (int u = 0; u < 4; ++u) A4[u] = chunk[u];

    auto PROC = [&](const float4* buf, int t) {
#pragma unroll
        for (int u = 0; u < 4; ++u) {
            float4 cc = buf[u];
            float s0 = fmaf(n0z, cc.z, fmaf(n0y, cc.y, fmaf(n0x, cc.x, cc.w)));
            float s1 = fmaf(n1z, cc.z, fmaf(n1y, cc.y, fmaf(n1x, cc.x, cc.w)));
            unsigned j = (unsigned)(jb + t + u);
            float f0 = __uint_as_float((__float_as_uint(s0) & 0xFFFFF000u) | j);
            float f1 = __uint_as_float((__float_as_uint(s1) & 0xFFFFF000u) | j);
#pragma unroll
            for (int k = KNN - 1; k >= 1; --k) l0[k] = med3f(f0, l0[k-1], l0[k]);
            l0[0] = fminf(f0, l0[0]);
#pragma unroll
            for (int k = KNN - 1; k >= 1; --k) l1[k] = med3f(f1, l1[k-1], l1[k]);
            l1[0] = fminf(f1, l1[0]);
        }
    };

    // Double-buffered scan over this half's 64 candidates (8 iterations)
#pragma unroll 1
    for (int t = 0; t < CPT; t += 8) {
#pragma unroll
        for (int u = 0; u < 4; ++u) B4[u] = chunk[t + 4 + u];
        PROC(A4, t);
        if (t + 8 < CPT) {
#pragma unroll
            for (int u = 0; u < 4; ++u) A4[u] = chunk[t + 8 + u];
        }
        PROC(B4, t + 4);
    }

    // ---- in-wave merge: 1 paired round, select parity, 4 single rounds ----
    merge_round(l0, 1);
    merge_round(l1, 1);
    const int sel = split & 1;
    float ml[KNN];
#pragma unroll
    for (int k = 0; k < KNN; ++k) ml[k] = sel ? l1[k] : l0[k];
    merge_round(ml, 2); merge_round(ml, 4); merge_round(ml, 8); merge_round(ml, 16);
    // even lanes hold (half's) q0 top-10, odd lanes q1's

    // ---- cross-half merge via LDS (lanes 0,1 of each group only) ----
    if (half == 1 && split < 2) {
#pragma unroll
        for (int k = 0; k < KNN; ++k) plist[qpair][split][k] = ml[k];
    }
    __syncthreads();
    if (half == 0 && split < 2) {
        float c[KNN];
#pragma unroll
        for (int i = 0; i < KNN; ++i)
            c[i] = fminf(ml[i], plist[qpair][split][KNN - 1 - i]);
        SORT10(c);
#pragma unroll
        for (int k = 0; k < KNN; ++k) qlists[qpair * 2 + split][k] = c[k];
    }
    __syncthreads();

    // ---- epilogue: one query per group (32 groups = 32 queries) ----
    const int qi = qb + group;
    const float4 Qe = spts[PIDX(qi)];
    const float eqx = -2.f*Qe.x, eqy = -2.f*Qe.y, eqz = -2.f*Qe.z;

    // distributed changingrate: lanes 0..9 handle one neighbor each
    float crk = 0.0f;
    if (split < KNN) {
        int j = (int)(__float_as_uint(qlists[group][split]) & 0xFFFu);
        float nx = xb[qi*6+3], ny = xb[qi*6+4], nz = xb[qi*6+5];
        float mx = xb[j*6+3],  my_ = xb[j*6+4],  mz = xb[j*6+5];
        float cx = ny*mz - nz*my_;
        float cy = nz*mx - nx*mz;
        float cz = nx*my_ - ny*mx;
        float c1 = sqrtf(cx*cx + cy*cy + cz*cz);
        float px = nx*mx, py = ny*my_, pz = nz*mz;
        float c2 = sqrtf(px*px + py*py + pz*pz);
        crk = fminf(c1, c2);
    }
#pragma unroll
    for (int m = 1; m <= 8; m <<= 1) crk += __shfl_xor(crk, m, 64);

    // top-2 skeleton scores for qi (32-lane split)
    float t0v = BIG, t1v = BIG;
    for (int m = split; m < NSKEL; m += 32) {
        float4 c = sskl[m];
        float s = fmaf(eqz, c.z, fmaf(eqy, c.y, fmaf(eqx, c.x, c.w)));
        t1v = med3f(s, t0v, t1v);    // uses old t0v
        t0v = fminf(s, t0v);
    }
#pragma unroll
    for (int m = 1; m <= 16; m <<= 1) {
        float o0 = __shfl_xor(t0v, m, 64);
        float o1 = __shfl_xor(t1v, m, 64);
        float nv = fminf(fmaxf(t0v, o0), fminf(t1v, o1));
        t0v = fminf(t0v, o0); t1v = nv;
    }
    // d2 gap == score gap (|q|^2 cancels); owner: split 0 of each group
    float contrib = (split == 0) ? crk * (t1v - t0v) : 0.0f;
    contrib += __shfl_down(contrib, 32);   // combine the wave's 2 groups
    if ((tid & 63) == 0) part[tid >> 6] = contrib;
    __syncthreads();
    if (tid == 0) {
        float s = 0.0f;
#pragma unroll
        for (int i = 0; i < 16; ++i) s += part[i];
        atomicAdd(out, s);
    }

    // ---- skeleton self-NN term, one block per batch ----
    if ((blockIdx.x & 127) == 0) {
        float v = 0.0f;
        if (tid < NSKEL) {
            float4 sq = sskl[tid];
            float b0 = BIG, b1 = BIG; int i0 = 0, i1 = 0;
            for (int jj = 0; jj < NSKEL; ++jj) {
                float4 c = sskl[jj];
                float s = c.w - 2.0f*(sq.x*c.x + sq.y*c.y + sq.z*c.z);
                if (s < b0)      { b1 = b0; i1 = i0; b0 = s; i0 = jj; }
                else if (s < b1) { b1 = s; i1 = jj; }
            }
            float4 c = sskl[i1];                 // knn_skele[..., 1]
            float dx = sq.x - c.x, dy = sq.y - c.y, dz = sq.z - c.z;
            v = sqrtf(dx*dx + dy*dy + dz*dz);
        }
#pragma unroll
        for (int o = 32; o > 0; o >>= 1) v += __shfl_down(v, o);
        if ((tid & 63) == 0 && tid < 128) atomicAdd(out, -0.5f * v);
    }
}

extern "C" void kernel_launch(void* const* d_in, const int* in_sizes, int n_in,
                              void* d_out, int out_size, void* d_ws, size_t ws_size,
                              hipStream_t stream) {
    const float* xyz  = (const float*)d_in[0];
    // d_in[1] = num_class (== NSKEL), compile-time constant here
    const float* skel = (const float*)d_in[2];
    float* out = (float*)d_out;

    hipMemsetAsync(out, 0, sizeof(float), stream);
    voronoi_kernel<<<BATCH * 128, 1024, 0, stream>>>(xyz, skel, out);
}